// Round 9
// baseline (31.082 us; speedup 1.0000x reference)
//
#include <hip/hip_runtime.h>

// HilbertFlatten: out[s] = x[hilbert_decode(s)] for (256,256,256) f32.
// 32 consecutive curve points per thread (4 cubes). ONE probe-decode
// (iterations bit=5..0 shared; bit=6 applied per-chunk as byte map M6).
// 16 independent float2 loads issued before any use (8KB/wave in flight).
// Stores: per-wave LDS transpose (swizzled 16B chunks, rotation (c+lane)&7)
// then 8 fully-contiguous 1KB nontemporal stores per wave (full-line).

typedef float f32x4 __attribute__((ext_vector_type(4)));

__global__ __launch_bounds__(256) void hilbert_g32t_kernel(
    const float* __restrict__ x, float* __restrict__ out) {
    __shared__ float lds[4 * 2048];          // 8KB per wave
    // XCD-chunked bijective swizzle (gridDim.x divisible by 8).
    unsigned nb = blockIdx.x;
    unsigned cpx = gridDim.x >> 3;
    unsigned b = (nb & 7u) * cpx + (nb >> 3);
    unsigned tid = threadIdx.x;
    unsigned gid = b * 256u + tid;
    unsigned S = gid << 5;                   // base curve index, mult of 32
    unsigned lane = tid & 63u;
    unsigned wave = tid >> 6;

    unsigned g = S ^ (S >> 1);
    unsigned G[3];
#pragma unroll
    for (int d = 0; d < 3; ++d) {
        unsigned v = (g >> (2 - d)) & 0x00249249u;
        v = (v ^ (v >> 2)) & 0x030C30C3u;
        v = (v ^ (v >> 4)) & 0x0300F00Fu;
        v = (v ^ (v >> 8)) & 0x000000FFu;
        G[d] = v;
    }
    // Probe channels: bits 8..10 identity basis, bit 11 affine constant.
    G[0] |= 0x100u; G[1] |= 0x200u; G[2] |= 0x400u;

    // Undo-loop iterations bit=5..0 (bit=6 handled per-chunk below).
#pragma unroll
    for (int bit = 5; bit >= 0; --bit) {
        const unsigned low = ((1u << (7 - bit)) - 1u) | 0x0F00u;
#pragma unroll
        for (int dim = 2; dim >= 0; --dim) {
            unsigned m = (G[dim] >> (7 - bit)) & 1u;
            unsigned diff = (G[0] ^ G[dim]) & low;
            unsigned t = diff & (m - 1u);
            G[0] ^= ((0u - m) & low) ^ t;
            G[dim] ^= t;
        }
    }

    unsigned cm[3], a0m[3], a1m[3], a2m[3];
#pragma unroll
    for (int d = 0; d < 3; ++d) {
        unsigned cd = 0u - ((G[d] >> 11) & 1u);
        cm[d] = cd;
        a0m[d] = (0u - ((G[d] >> 8) & 1u)) ^ cd;
        a1m[d] = (0u - ((G[d] >> 9) & 1u)) ^ cd;
        a2m[d] = (0u - ((G[d] >> 10) & 1u)) ^ cd;
    }

    unsigned S5 = (S >> 5) & 1u, S6 = (S >> 6) & 1u;
    unsigned u0 = S5 ^ S6;                   // initial G0.bit1 (all chunks)

    unsigned bases[4], Bb[4][3];
#pragma unroll
    for (int c = 0; c < 4; ++c) {
        unsigned c0 = (unsigned)c & 1u, c1 = ((unsigned)c >> 1) & 1u;
        unsigned u2 = c0 ^ c1;               // initial G2.bit1
        unsigned u1 = c1 ^ S5;               // initial G1.bit1
        unsigned V0 = 0xF0u ^ ((0u - c0) & 0xFFu);
        unsigned V1 = 0x3Cu, V2 = 0x66u;
        // M6 = undo iteration bit=6 (masks = init bit1):
        unsigned mm = (0u - u2) & 0xFFu;
        unsigned t = (V0 ^ V2) & (mm ^ 0xFFu);
        V0 ^= mm ^ t;  V2 ^= t;
        mm = (0u - u1) & 0xFFu;
        t = (V0 ^ V1) & (mm ^ 0xFFu);
        V0 ^= mm ^ t;  V1 ^= t;
        V0 ^= (0u - u0) & 0xFFu;
#pragma unroll
        for (int d = 0; d < 3; ++d)
            Bb[c][d] = ((a0m[d] & V0) ^ (a1m[d] & V1) ^ (a2m[d] & V2)
                        ^ cm[d]) & 0xFFu;
        unsigned b1x = ((a0m[0] & u0) ^ (a1m[0] & u1) ^ (a2m[0] & u2) ^ cm[0]) & 1u;
        unsigned b1y = ((a0m[1] & u0) ^ (a1m[1] & u1) ^ (a2m[1] & u2) ^ cm[1]) & 1u;
        unsigned b1z = ((a0m[2] & u0) ^ (a1m[2] & u1) ^ (a2m[2] & u2) ^ cm[2]) & 1u;
        unsigned cx = (G[0] & 0xFCu) | (b1x << 1);
        unsigned cy = (G[1] & 0xFCu) | (b1y << 1);
        unsigned cz = (G[2] & 0xFCu) | (b1z << 1);
        bases[c] = (cx << 16) | (cy << 8) | cz;   // bit0s zero -> 8B aligned
    }

    // Issue ALL 16 loads before any use (8KB/wave outstanding).
    float2 p[4][4];
#pragma unroll
    for (int c = 0; c < 4; ++c) {
        const float2* xp = (const float2*)(x + bases[c]);
        p[c][0] = xp[0];
        p[c][1] = xp[128];
        p[c][2] = xp[32768];
        p[c][3] = xp[32768 + 128];
    }

    // Resolve curve order; write 16B chunks to LDS (rotated by lane).
    float* lw = lds + wave * 2048u;
#pragma unroll
    for (int c = 0; c < 4; ++c) {
        float o8[8];
#pragma unroll
        for (int r = 0; r < 8; ++r) {
            unsigned f0 = (Bb[c][0] >> r) & 1u;
            unsigned f1 = (Bb[c][1] >> r) & 1u;
            unsigned f2 = (Bb[c][2] >> r) & 1u;
            float2 t0 = f1 ? p[c][1] : p[c][0];
            float2 t1 = f1 ? p[c][3] : p[c][2];
            float2 t  = f0 ? t1 : t0;
            o8[r] = f2 ? t.y : t.x;
        }
#pragma unroll
        for (int h = 0; h < 2; ++h) {
            unsigned cc = (unsigned)c * 2u + (unsigned)h;      // chunk 0..7
            f32x4 v = {o8[h * 4], o8[h * 4 + 1], o8[h * 4 + 2], o8[h * 4 + 3]};
            *(f32x4*)&lw[lane * 32u + ((cc + lane) & 7u) * 4u] = v;
        }
    }
    __syncthreads();

    // Read back contiguous 1KB per store; 8 NT full-line stores per wave.
    unsigned WB = (b * 256u + wave * 64u) * 32u;   // wave's first out float
#pragma unroll
    for (unsigned k = 0; k < 8; ++k) {
        unsigned tsrc = 8u * k + (lane >> 3);      // owner thread row
        unsigned csrc = lane & 7u;                 // chunk within row
        f32x4 v = *(const f32x4*)&lw[tsrc * 32u + ((csrc + tsrc) & 7u) * 4u];
        __builtin_nontemporal_store(v, (f32x4*)(out + WB + k * 256u + 4u * lane));
    }
}

extern "C" void kernel_launch(void* const* d_in, const int* in_sizes, int n_in,
                              void* d_out, int out_size, void* d_ws, size_t ws_size,
                              hipStream_t stream) {
    const float* x = (const float*)d_in[0];
    float* out = (float*)d_out;
    unsigned n = (unsigned)out_size;            // 16777216
    unsigned threads = n >> 5;                  // 524288 (32 pts/thread)
    unsigned blocks = threads / 256u;           // 2048 (divisible by 8)
    hilbert_g32t_kernel<<<blocks, 256, 0, stream>>>(x, out);
}

// Round 10
// 26.610 us; speedup vs baseline: 1.1681x; 1.1681x over previous
//
#include <hip/hip_runtime.h>

// HilbertFlatten: out[s] = x[hilbert_decode(s)] for (256,256,256) f32.
// Per wave: TWO 8^3 regions (1024 consecutive curve points). 4x
// global_load_lds (16B/lane) issued back-to-back -> 4KB/wave in flight,
// one s_waitcnt vmcnt(0), no __syncthreads (wave-private LDS slices).
// Lanes gather their 2x2x2 cube from LDS (corner-rotation, conflict-free
// per R3), resolve curve order via cndmask tree, then shuffle-pair into
// fully-contiguous 1KB nontemporal stores (full-line, per R7).

typedef float f32x4 __attribute__((ext_vector_type(4)));
typedef __attribute__((address_space(1))) const void global_cvoid;
typedef __attribute__((address_space(3))) void lds_void;

__device__ __forceinline__ void decode8(unsigned S, unsigned B[3],
                                        unsigned& baseflat) {
    unsigned g = S ^ (S >> 1);
    unsigned G[3];
#pragma unroll
    for (int d = 0; d < 3; ++d) {
        unsigned v = (g >> (2 - d)) & 0x00249249u;
        v = (v ^ (v >> 2)) & 0x030C30C3u;
        v = (v ^ (v >> 4)) & 0x0300F00Fu;
        v = (v ^ (v >> 8)) & 0x000000FFu;
        G[d] = v;
    }
    G[0] |= 0x100u; G[1] |= 0x200u; G[2] |= 0x400u;
#pragma unroll
    for (int bit = 6; bit >= 0; --bit) {
        const unsigned low = ((1u << (7 - bit)) - 1u) | 0x0F00u;
#pragma unroll
        for (int dim = 2; dim >= 0; --dim) {
            unsigned m = (G[dim] >> (7 - bit)) & 1u;
            unsigned diff = (G[0] ^ G[dim]) & low;
            unsigned t = diff & (m - 1u);
            G[0] ^= ((0u - m) & low) ^ t;
            G[dim] ^= t;
        }
    }
    unsigned s3m = 0u - ((S >> 3) & 1u);
    unsigned V0 = (0xF0u ^ s3m) & 0xFFu;
    const unsigned V1 = 0x3Cu, V2 = 0x66u;
#pragma unroll
    for (int d = 0; d < 3; ++d) {
        unsigned cd = 0u - ((G[d] >> 11) & 1u);
        unsigned a0 = (0u - ((G[d] >> 8) & 1u)) ^ cd;
        unsigned a1 = (0u - ((G[d] >> 9) & 1u)) ^ cd;
        unsigned a2 = (0u - ((G[d] >> 10) & 1u)) ^ cd;
        B[d] = ((a0 & V0) ^ (a1 & V1) ^ (a2 & V2) ^ cd) & 0xFFu;
    }
    baseflat = ((G[0] & 0xFEu) << 16) | ((G[1] & 0xFEu) << 8) | (G[2] & 0xFEu);
}

__global__ __launch_bounds__(256) void hilbert_r2_kernel(
    const float* __restrict__ x, float* __restrict__ out) {
    __shared__ float lds[4 * 1024];          // 4KB per wave (2 regions)
    // XCD-chunked bijective swizzle (gridDim.x = 4096, divisible by 8).
    unsigned nb = blockIdx.x;
    unsigned cpx = gridDim.x >> 3;
    unsigned b = (nb & 7u) * cpx + (nb >> 3);
    unsigned tid = threadIdx.x;
    unsigned lane = tid & 63u;
    unsigned wave = tid >> 6;
    unsigned W = b * 4u + wave;              // global wave id
    unsigned Sw = W * 1024u;                 // wave's first curve point

    // Decode both cubes (independent ILP chains).
    unsigned B0[3], B1[3], bf0, bf1;
    decode8(Sw + lane * 8u, B0, bf0);
    decode8(Sw + 512u + lane * 8u, B1, bf1);

    // Issue all 4 region loads (wave-uniform LDS dst, per-lane global src).
    unsigned dxl = lane >> 4;
    unsigned dyl = (lane >> 1) & 7u;
    unsigned half = lane & 1u;
    auto lds3 = (__attribute__((address_space(3))) float*)lds;
    unsigned rf0 = bf0 & 0x00F8F8F8u;
    unsigned rf1 = bf1 & 0x00F8F8F8u;
#pragma unroll
    for (unsigned q = 0; q < 2; ++q) {
        const float* gbase = x + (q ? rf1 : rf0);
#pragma unroll
        for (unsigned h = 0; h < 2; ++h) {
            const float* src = gbase + (h * 4u + dxl) * 65536u
                             + dyl * 256u + half * 4u;
            __builtin_amdgcn_global_load_lds(
                (global_cvoid*)src,
                (lds_void*)(lds3 + wave * 1024u + q * 512u + h * 256u),
                16, 0, 0);
        }
    }
    asm volatile("s_waitcnt vmcnt(0)" ::: "memory");

#pragma unroll
    for (unsigned q = 0; q < 2; ++q) {
        unsigned baseflat = q ? bf1 : bf0;
        const unsigned* B = q ? B1 : B0;
        unsigned bx = (baseflat >> 16) & 6u;
        unsigned by = (baseflat >> 8) & 6u;
        unsigned bz = baseflat & 6u;
        unsigned bxp = (bx >> 1) & 1u;
        unsigned byp = (by >> 1) & 1u;
        const float* lw = lds + wave * 1024u + q * 512u;
        // corner-rotation read order (conflict-free per R3)
        float2 r0 = *(const float2*)&lw[(bx + byp) * 64u + (by + bxp) * 8u + bz];
        float2 r1 = *(const float2*)&lw[(bx + byp) * 64u + (by + (bxp ^ 1u)) * 8u + bz];
        float2 r2 = *(const float2*)&lw[(bx + (byp ^ 1u)) * 64u + (by + bxp) * 8u + bz];
        float2 r3 = *(const float2*)&lw[(bx + (byp ^ 1u)) * 64u + (by + (bxp ^ 1u)) * 8u + bz];
        bool sx = bxp != 0u, sy = byp != 0u;
        float2 a0 = sx ? r1 : r0;
        float2 a1 = sx ? r0 : r1;
        float2 a2 = sx ? r3 : r2;
        float2 a3 = sx ? r2 : r3;
        float2 q00 = sy ? a2 : a0;
        float2 q01 = sy ? a3 : a1;
        float2 q10 = sy ? a0 : a2;
        float2 q11 = sy ? a1 : a3;

        float o8[8];
#pragma unroll
        for (int rr = 0; rr < 8; ++rr) {
            unsigned f0 = (B[0] >> rr) & 1u;
            unsigned f1 = (B[1] >> rr) & 1u;
            unsigned f2 = (B[2] >> rr) & 1u;
            float2 t0 = f1 ? q01 : q00;
            float2 t1 = f1 ? q11 : q10;
            float2 t  = f0 ? t1 : t0;
            o8[rr] = f2 ? t.y : t.x;
        }

        // Shuffle-paired fully-contiguous NT stores (2 x 1KB per region).
        int src1 = (int)(lane >> 1);
        int src2 = (int)(32u + (lane >> 1));
        bool hi = (lane & 1u) != 0u;
        float vA[4], vB[4];
#pragma unroll
        for (int j = 0; j < 4; ++j) {
            float a = __shfl(o8[j], src1, 64);
            float bb = __shfl(o8[4 + j], src1, 64);
            vA[j] = hi ? bb : a;
            float c = __shfl(o8[j], src2, 64);
            float d = __shfl(o8[4 + j], src2, 64);
            vB[j] = hi ? d : c;
        }
        unsigned WB = Sw + q * 512u;
        __builtin_nontemporal_store((f32x4){vA[0], vA[1], vA[2], vA[3]},
                                    (f32x4*)(out + WB + 4u * lane));
        __builtin_nontemporal_store((f32x4){vB[0], vB[1], vB[2], vB[3]},
                                    (f32x4*)(out + WB + 256u + 4u * lane));
    }
}

extern "C" void kernel_launch(void* const* d_in, const int* in_sizes, int n_in,
                              void* d_out, int out_size, void* d_ws, size_t ws_size,
                              hipStream_t stream) {
    const float* x = (const float*)d_in[0];
    float* out = (float*)d_out;
    unsigned n = (unsigned)out_size;            // 16777216
    unsigned nwaves = n / 1024u;                // 16384 (1024 pts per wave)
    unsigned blocks = nwaves / 4u;              // 4096 (divisible by 8)
    hilbert_r2_kernel<<<blocks, 256, 0, stream>>>(x, out);
}